// Round 3
// baseline (304.148 us; speedup 1.0000x reference)
//
#include <hip/hip_runtime.h>
#include <cstdint>

namespace {

constexpr int BPB  = 64;     // batches per block
constexpr int NTHR = 128;    // wave0: bwd chain; wave1: fwd chain (fully independent)
constexpr int RSTR = 37;     // LDS row stride in floats (odd -> conflict-free b32 r/w)
constexpr int ROWF = 567;    // floats per R_mode batch row (63*9)
constexpr int OUTF = 192;    // floats per output batch row (64*3)

__device__ __forceinline__ float sigm_(float x) {
    return __fdividef(1.0f, 1.0f + __expf(-x));
}
__device__ __forceinline__ float tanh_(float x) {
    return __fdividef(2.0f, 1.0f + __expf(-2.0f * x)) - 1.0f;
}

// same-wave LDS write->read fence (no __syncthreads: waves never share LDS)
__device__ __forceinline__ void lds_fence() {
    asm volatile("s_waitcnt lgkmcnt(0)" ::: "memory");
    __builtin_amdgcn_sched_barrier(0);
}

// Issue the 9 coalesced float4 loads for one 4-timestep chunk (36 floats x 64 batches).
__device__ __forceinline__ void issue9(const float* __restrict__ Rg, int64_t b0,
                                       int lane, int t0f, bool clamp, int64_t ntot,
                                       float4* nxt) {
    #pragma unroll
    for (int k = 0; k < 9; ++k) {
        const int f4  = k * 64 + lane;          // 576 float4 = 64 segs x 9
        const int seg = f4 / 9;
        const int off = f4 - seg * 9;
        int64_t g = (b0 + seg) * (int64_t)ROWF + t0f + off * 4;
        if (clamp && g > ntot - 4) g = ntot - 4;   // tail chunk: stay inside array
        nxt[k] = *reinterpret_cast<const float4*>(Rg + g);
    }
}

// Scatter the prefetched regs into this wave's LDS buffer (b32, conflict-free pad).
__device__ __forceinline__ void write9(float* __restrict__ buf, int lane,
                                       const float4* nxt) {
    #pragma unroll
    for (int k = 0; k < 9; ++k) {
        const int f4  = k * 64 + lane;
        const int seg = f4 / 9;
        const int off = f4 - seg * 9;
        float* p = buf + seg * RSTR + off * 4;
        p[0] = nxt[k].x; p[1] = nxt[k].y; p[2] = nxt[k].z; p[3] = nxt[k].w;
    }
}

// flush one completed 64-B sector (16 floats) as 4 aligned float4 stores
__device__ __forceinline__ void flush16(float* __restrict__ dst, const float* __restrict__ buf) {
    #pragma unroll
    for (int q = 0; q < 4; ++q)
        *reinterpret_cast<float4*>(dst + 4 * q) =
            make_float4(buf[4*q+0], buf[4*q+1], buf[4*q+2], buf[4*q+3]);
}

__global__ __launch_bounds__(NTHR, 2) void gaze_kernel(
    const float* __restrict__ dirg,   // (B,3)
    const float* __restrict__ Rg,     // (B,63,3,3)
    float* __restrict__ outg,         // (B,64,3)
    int64_t ntot)                     // B*567
{
    __shared__ float ldsR[2][2][BPB * RSTR];   // [wave][dbuf]  37.9 KB total

    const int tid  = threadIdx.x;
    const int wid  = tid >> 6;
    const int lane = tid & 63;
    const int64_t b0 = (int64_t)blockIdx.x * BPB;
    const int64_t b  = b0 + lane;

    const float dx = dirg[b * 3 + 0];
    const float dy = dirg[b * 3 + 1];
    const float dz = dirg[b * 3 + 2];

    float M[9] = {1.f, 0.f, 0.f, 0.f, 1.f, 0.f, 0.f, 0.f, 1.f};
    float bufE[16], bufO[16];          // even / odd sector staging (compile-time idx only)
    float* orow = outg + b * OUTF;

    // per-float scatter into sector buffers; f is compile-time after unroll
    #define PUT3(F0, VX, VY, VZ)                                              \
        do {                                                                  \
            { const int f_ = (F0);                                            \
              if ((((f_ >> 4) & 1) == 0)) bufE[f_ & 15] = (VX);               \
              else                         bufO[f_ & 15] = (VX); }            \
            { const int f_ = (F0) + 1;                                        \
              if ((((f_ >> 4) & 1) == 0)) bufE[f_ & 15] = (VY);               \
              else                         bufO[f_ & 15] = (VY); }            \
            { const int f_ = (F0) + 2;                                        \
              if ((((f_ >> 4) & 1) == 0)) bufE[f_ & 15] = (VZ);               \
              else                         bufO[f_ & 15] = (VZ); }            \
        } while (0)

    if (wid == 0) {
        // ---------------- wave0: bwd chain t=31..0 -> out floats 95..0 (sectors 5..0)
        float* const L0 = &ldsR[0][0][0];
        float* const L1 = &ldsR[0][1][0];
        float4 pfA[9], pfB[9];
        issue9(Rg, b0, lane, 7 * 36, false, ntot, pfA);   // chunk0 (t0=28)
        issue9(Rg, b0, lane, 6 * 36, false, ntot, pfB);   // chunk1 (t0=24)
        write9(L0, lane, pfA);

        #pragma unroll
        for (int c = 0; c < 8; ++c) {
            if (c + 2 < 8) {   // prefetch chunk c+2 into the reg set freed last iter
                if ((c & 1) == 0) issue9(Rg, b0, lane, (5 - c) * 36, false, ntot, pfA);
                else              issue9(Rg, b0, lane, (5 - c) * 36, false, ntot, pfB);
            }
            if (c + 1 < 8) {   // stage chunk c+1 (counted vmcnt from compiler)
                if ((c & 1) == 0) write9(L1, lane, pfB);
                else              write9(L0, lane, pfA);
            }
            lds_fence();
            const float* row = (((c & 1) == 0) ? L0 : L1) + lane * RSTR;
            const int t0 = (7 - c) * 4;
            #pragma unroll
            for (int s = 0; s < 4; ++s) {
                const int tt = 3 - s;                    // descending t within chunk
                const float* Rl = row + tt * 9;
                const float r00=Rl[0], r01=Rl[1], r02=Rl[2];
                const float r10=Rl[3], r11=Rl[4], r12=Rl[5];
                const float r20=Rl[6], r21=Rl[7], r22=Rl[8];
                float n0, n1, n2;
                // M <- M @ R^T
                n0 = M[0]*r00 + M[1]*r01 + M[2]*r02;
                n1 = M[0]*r10 + M[1]*r11 + M[2]*r12;
                n2 = M[0]*r20 + M[1]*r21 + M[2]*r22;
                M[0]=n0; M[1]=n1; M[2]=n2;
                n0 = M[3]*r00 + M[4]*r01 + M[5]*r02;
                n1 = M[3]*r10 + M[4]*r11 + M[5]*r12;
                n2 = M[3]*r20 + M[4]*r21 + M[5]*r22;
                M[3]=n0; M[4]=n1; M[5]=n2;
                n0 = M[6]*r00 + M[7]*r01 + M[8]*r02;
                n1 = M[6]*r10 + M[7]*r11 + M[8]*r12;
                n2 = M[6]*r20 + M[7]*r21 + M[8]*r22;
                M[6]=n0; M[7]=n1; M[8]=n2;
                const int t = t0 + tt;
                const float vx = M[0]*dx + M[1]*dy + M[2]*dz;
                const float vy = M[3]*dx + M[4]*dy + M[5]*dz;
                const float vz = M[6]*dx + M[7]*dy + M[8]*dz;
                PUT3(3 * t, vx, vy, vz);
                // sector completions (t descending): flush exactly when full
                if (t == 26) flush16(orow + 80, bufO);   // sector 5
                if (t == 21) flush16(orow + 64, bufE);   // sector 4
                if (t == 16) flush16(orow + 48, bufO);   // sector 3
                if (t == 10) flush16(orow + 32, bufE);   // sector 2
                if (t == 5)  flush16(orow + 16, bufO);   // sector 1
                if (t == 0)  flush16(orow +  0, bufE);   // sector 0
            }
        }
    } else {
        // ---------------- wave1: fwd chain t=32..62 -> out floats 96..191 (sectors 6..11)
        float* const L0 = &ldsR[1][0][0];
        float* const L1 = &ldsR[1][1][0];
        float4 pfA[9], pfB[9];
        issue9(Rg, b0, lane, 288 +  0, false, ntot, pfA);   // chunk0 (t0=32)
        issue9(Rg, b0, lane, 288 + 36, false, ntot, pfB);   // chunk1 (t0=36)
        write9(L0, lane, pfA);

        // floats 96..98 = dir (t=32 slot; LSTM kernel overwrites with h later)
        PUT3(96, dx, dy, dz);

        #pragma unroll
        for (int c = 0; c < 8; ++c) {
            if (c + 2 < 8) {
                const int  t0f = 288 + (c + 2) * 36;
                const bool cl  = (c + 2 == 7);   // last chunk has only 3 mats
                if ((c & 1) == 0) issue9(Rg, b0, lane, t0f, cl, ntot, pfA);
                else              issue9(Rg, b0, lane, t0f, cl, ntot, pfB);
            }
            if (c + 1 < 8) {
                if ((c & 1) == 0) write9(L1, lane, pfB);
                else              write9(L0, lane, pfA);
            }
            lds_fence();
            const float* row = (((c & 1) == 0) ? L0 : L1) + lane * RSTR;
            #pragma unroll
            for (int tt = 0; tt < 4; ++tt) {
                if (tt < ((c < 7) ? 4 : 3)) {           // folds at compile time
                    const float* Rl = row + tt * 9;
                    const float r00=Rl[0], r01=Rl[1], r02=Rl[2];
                    const float r10=Rl[3], r11=Rl[4], r12=Rl[5];
                    const float r20=Rl[6], r21=Rl[7], r22=Rl[8];
                    float n0, n1, n2;
                    // P <- P @ R
                    n0 = M[0]*r00 + M[1]*r10 + M[2]*r20;
                    n1 = M[0]*r01 + M[1]*r11 + M[2]*r21;
                    n2 = M[0]*r02 + M[1]*r12 + M[2]*r22;
                    M[0]=n0; M[1]=n1; M[2]=n2;
                    n0 = M[3]*r00 + M[4]*r10 + M[5]*r20;
                    n1 = M[3]*r01 + M[4]*r11 + M[5]*r21;
                    n2 = M[3]*r02 + M[4]*r12 + M[5]*r22;
                    M[3]=n0; M[4]=n1; M[5]=n2;
                    n0 = M[6]*r00 + M[7]*r10 + M[8]*r20;
                    n1 = M[6]*r01 + M[7]*r11 + M[8]*r21;
                    n2 = M[6]*r02 + M[7]*r12 + M[8]*r22;
                    M[6]=n0; M[7]=n1; M[8]=n2;
                    const int oi = c * 4 + tt;          // 0..30, out float base 99+3*oi
                    const float vx = M[0]*dx + M[1]*dy + M[2]*dz;
                    const float vy = M[3]*dx + M[4]*dy + M[5]*dz;
                    const float vz = M[6]*dx + M[7]*dy + M[8]*dz;
                    PUT3(99 + 3 * oi, vx, vy, vz);
                    // sector completions (f ascending): flush when top float written
                    if (oi == 4)  flush16(orow +  96, bufE);  // sector 6  (f111)
                    if (oi == 9)  flush16(orow + 112, bufO);  // sector 7  (f127)
                    if (oi == 14) flush16(orow + 128, bufE);  // sector 8  (f143)
                    if (oi == 20) flush16(orow + 144, bufO);  // sector 9  (f159)
                    if (oi == 25) flush16(orow + 160, bufE);  // sector 10 (f175)
                    if (oi == 30) flush16(orow + 176, bufO);  // sector 11 (f191)
                }
            }
        }
    }
    #undef PUT3
}

// ---- kernel 2: tiny LSTM over dirs[0..32] (row floats 0..98, just written, L2/L3-warm)
__global__ __launch_bounds__(256, 1) void lstm_kernel(
    const float* __restrict__ w_ih,   // (12,3)
    const float* __restrict__ w_hh,   // (12,3)
    const float* __restrict__ b_ih,   // (12)
    const float* __restrict__ b_hh,   // (12)
    float* __restrict__ outg)         // (B,64,3)
{
    const int64_t b = (int64_t)blockIdx.x * blockDim.x + threadIdx.x;
    float* row = outg + b * OUTF;

    float4 v[25];                     // floats 0..99 (96..98 = dir = x_32)
    #pragma unroll
    for (int q = 0; q < 25; ++q) v[q] = *reinterpret_cast<const float4*>(row + 4 * q);

    float wi[12][3], wh[12][3], bsum[12];
    #pragma unroll
    for (int g = 0; g < 12; ++g) {    // uniform -> scalar loads
        wi[g][0] = w_ih[g*3+0]; wi[g][1] = w_ih[g*3+1]; wi[g][2] = w_ih[g*3+2];
        wh[g][0] = w_hh[g*3+0]; wh[g][1] = w_hh[g*3+1]; wh[g][2] = w_hh[g*3+2];
        bsum[g]  = b_ih[g] + b_hh[g];
    }

    // compile-time float4 component picker
    #define GETF(F) ((((F) & 3) == 0) ? v[(F) >> 2].x : (((F) & 3) == 1) ? v[(F) >> 2].y \
                    : (((F) & 3) == 2) ? v[(F) >> 2].z : v[(F) >> 2].w)

    float h[3]  = {0.f, 0.f, 0.f};
    float cc[3] = {0.f, 0.f, 0.f};
    #pragma unroll
    for (int t = 0; t < 33; ++t) {
        const float x0 = GETF(3 * t + 0);
        const float x1 = GETF(3 * t + 1);
        const float x2 = GETF(3 * t + 2);
        float ga[12];
        #pragma unroll
        for (int g = 0; g < 12; ++g)
            ga[g] = bsum[g] + wi[g][0]*x0 + wi[g][1]*x1 + wi[g][2]*x2
                            + wh[g][0]*h[0] + wh[g][1]*h[1] + wh[g][2]*h[2];
        float ig[3], fg[3], gg[3], og[3];
        #pragma unroll
        for (int j = 0; j < 3; ++j) {
            ig[j] = sigm_(ga[j]);
            fg[j] = sigm_(ga[3 + j]);
            gg[j] = tanh_(ga[6 + j]);
            og[j] = sigm_(ga[9 + j]);
        }
        #pragma unroll
        for (int j = 0; j < 3; ++j) {
            cc[j] = fg[j] * cc[j] + ig[j] * gg[j];
            h[j]  = og[j] * tanh_(cc[j]);
        }
    }
    #undef GETF

    row[96] = h[0]; row[97] = h[1]; row[98] = h[2];
}

}  // namespace

extern "C" void kernel_launch(void* const* d_in, const int* in_sizes, int n_in,
                              void* d_out, int out_size, void* d_ws, size_t ws_size,
                              hipStream_t stream) {
    const float* dirg = (const float*)d_in[0];
    const float* Rg   = (const float*)d_in[1];
    // d_in[2] = S_diag: unused by the reference forward
    const float* wih  = (const float*)d_in[3];
    const float* whh  = (const float*)d_in[4];
    const float* bih  = (const float*)d_in[5];
    const float* bhh  = (const float*)d_in[6];
    float* outg = (float*)d_out;

    const int B = in_sizes[0] / 3;              // 65536
    const int64_t ntot = (int64_t)in_sizes[1];  // B*567
    gaze_kernel<<<B / BPB, NTHR, 0, stream>>>(dirg, Rg, outg, ntot);
    lstm_kernel<<<B / 256, 256, 0, stream>>>(wih, whh, bih, bhh, outg);
}